// Round 3
// baseline (778.656 us; speedup 1.0000x reference)
//
#include <hip/hip_runtime.h>
#include <hip/hip_bf16.h>
#include <math.h>

#define BATCH 8192
#define HID   4096
#define KDIM  512
#define OUT   1024

#define BM     128
#define BK     16
#define PAD    132
#define NCHUNK 8
#define CHUNKW 512   // HID / NCHUNK
#define NSUB   4     // CHUNKW / BM

__device__ __forceinline__ void top2_upd(float v, int idx, float& v1, int& i1,
                                         float& v2, int& i2) {
  if (v < v1 || (v == v1 && idx < i1)) { v2 = v1; i2 = i1; v1 = v; i1 = idx; }
  else if (v < v2 || (v == v2 && idx < i2)) { v2 = v; i2 = idx; }
}

// ---------------- w2[j] = sum_k W[j,k]^2 (f32, approx pass only) --------------
__global__ void __launch_bounds__(64)
w2_kernel(const float* __restrict__ W, float* __restrict__ w2) {
  int j = blockIdx.x, lane = threadIdx.x;
  const float4* row = (const float4*)(W + (size_t)j * KDIM);
  float s = 0.f;
#pragma unroll
  for (int i = 0; i < 2; ++i) {
    float4 v = row[lane + i * 64];
    s += v.x * v.x + v.y * v.y + v.z * v.z + v.w * v.w;
  }
#pragma unroll
  for (int off = 32; off; off >>= 1) s += __shfl_down(s, off);
  if (lane == 0) w2[j] = s;
}

// -------- fused f32 GEMM (dot(x,w)) + per-row top-2 of (w2 - 2*dot) ----------
// grid 512 = 64 row-blocks x 8 H-chunks; chunk = bid&7 -> one W-chunk per XCD L2
__global__ void __launch_bounds__(256)
dist_argmin_kernel(const float* __restrict__ X, const float* __restrict__ W,
                   const float* __restrict__ w2, float4* __restrict__ partials) {
  __shared__ float xs[BK][PAD];
  __shared__ float ws_[BK][PAD];

  const int tid = threadIdx.x;
  const int tx = tid & 15, ty = tid >> 4;
  const int rb = blockIdx.x >> 3, chunk = blockIdx.x & 7;
  const int row0 = rb * BM;
  const int col0 = chunk * CHUNKW;

  float v1[8], v2[8];
  int i1[8], i2[8];
#pragma unroll
  for (int i = 0; i < 8; ++i) { v1[i] = v2[i] = 3.4e38f; i1[i] = i2[i] = 0x7fffffff; }

  for (int st = 0; st < NSUB; ++st) {
    const int cbase = col0 + st * BM;
    float acc[8][8];
#pragma unroll
    for (int i = 0; i < 8; ++i)
#pragma unroll
      for (int j = 0; j < 8; ++j) acc[i][j] = 0.f;

    for (int k0 = 0; k0 < KDIM; k0 += BK) {
      // stage x[row0..+128][k0..+16] and W[cbase..+128][k0..+16], k-major in LDS
#pragma unroll
      for (int h = 0; h < 2; ++h) {
        int t = tid + h * 256;
        int r = t >> 2;
        int kk = (t & 3) * 4;
        float4 xv = *(const float4*)(X + (size_t)(row0 + r) * KDIM + k0 + kk);
        xs[kk + 0][r] = xv.x; xs[kk + 1][r] = xv.y;
        xs[kk + 2][r] = xv.z; xs[kk + 3][r] = xv.w;
        float4 wv = *(const float4*)(W + (size_t)(cbase + r) * KDIM + k0 + kk);
        ws_[kk + 0][r] = wv.x; ws_[kk + 1][r] = wv.y;
        ws_[kk + 2][r] = wv.z; ws_[kk + 3][r] = wv.w;
      }
      __syncthreads();
#pragma unroll
      for (int kk = 0; kk < BK; ++kk) {
        // LDS float4 loads (16B-aligned: row stride 132*4=528=33*16, col off 32B)
        float4 a0 = *(const float4*)&xs[kk][ty * 8];
        float4 a1 = *(const float4*)&xs[kk][ty * 8 + 4];
        float4 b0 = *(const float4*)&ws_[kk][tx * 8];
        float4 b1 = *(const float4*)&ws_[kk][tx * 8 + 4];
        float a[8], b[8];
        a[0] = a0.x; a[1] = a0.y; a[2] = a0.z; a[3] = a0.w;
        a[4] = a1.x; a[5] = a1.y; a[6] = a1.z; a[7] = a1.w;
        b[0] = b0.x; b[1] = b0.y; b[2] = b0.z; b[3] = b0.w;
        b[4] = b1.x; b[5] = b1.y; b[6] = b1.z; b[7] = b1.w;
#pragma unroll
        for (int i = 0; i < 8; ++i)
#pragma unroll
          for (int j = 0; j < 8; ++j)
            acc[i][j] = fmaf(a[i], b[j], acc[i][j]);
      }
      __syncthreads();
    }
    // fold this 128-col subtile into per-thread top-2
#pragma unroll
    for (int j = 0; j < 8; ++j) {
      int col = cbase + tx * 8 + j;
      float w2c = w2[col];
#pragma unroll
      for (int i = 0; i < 8; ++i) {
        float v = fmaf(-2.f, acc[i][j], w2c);  // x^2 row-constant: irrelevant to argmin
        top2_upd(v, col, v1[i], i1[i], v2[i], i2[i]);
      }
    }
  }

  // merge top-2 across the 16 tx-threads of each ty-group via in-wave butterfly
  // (lane = (ty&3)*16 + tx; xor masks 1,2,4,8 permute tx only)
#pragma unroll
  for (int m = 1; m < 16; m <<= 1) {
#pragma unroll
    for (int i = 0; i < 8; ++i) {
      float ov1 = __shfl_xor(v1[i], m);
      float ov2 = __shfl_xor(v2[i], m);
      int oi1 = __shfl_xor(i1[i], m);
      int oi2 = __shfl_xor(i2[i], m);
      top2_upd(ov1, oi1, v1[i], i1[i], v2[i], i2[i]);
      top2_upd(ov2, oi2, v1[i], i1[i], v2[i], i2[i]);
    }
  }
  if (tx == 0) {
#pragma unroll
    for (int i = 0; i < 8; ++i) {
      partials[(size_t)(row0 + ty * 8 + i) * NCHUNK + chunk] =
          make_float4(v1[i], v2[i], __int_as_float(i1[i]), __int_as_float(i2[i]));
    }
  }
}

// ------- merge chunk partials; fp64 recheck of top-2; emit winner ------------
__global__ void __launch_bounds__(256)
recheck_kernel(const float* __restrict__ X, const float* __restrict__ W,
               const float4* __restrict__ partials, int* __restrict__ win,
               float* __restrict__ out_idx) {
  int lane = threadIdx.x & 63;
  int b = blockIdx.x * 4 + (threadIdx.x >> 6);
  float bv1 = 3.4e38f, bv2 = 3.4e38f;
  int bi1 = 0x7fffffff, bi2 = 0x7fffffff;
#pragma unroll
  for (int c = 0; c < NCHUNK; ++c) {
    float4 p = partials[(size_t)b * NCHUNK + c];
    top2_upd(p.x, __float_as_int(p.z), bv1, bi1, bv2, bi2);
    top2_upd(p.y, __float_as_int(p.w), bv1, bi1, bv2, bi2);
  }
  const float* xr  = X + (size_t)b * KDIM;
  const float* wr1 = W + (size_t)bi1 * KDIM;
  const float* wr2 = W + (size_t)bi2 * KDIM;
  double s1 = 0.0, s2 = 0.0;
#pragma unroll
  for (int i = 0; i < KDIM / 64; ++i) {
    int k = lane + i * 64;
    double xv = (double)xr[k];
    double d1 = xv - (double)wr1[k];
    double d2 = xv - (double)wr2[k];
    s1 += d1 * d1;
    s2 += d2 * d2;
  }
#pragma unroll
  for (int off = 32; off; off >>= 1) {
    s1 += __shfl_down(s1, off);
    s2 += __shfl_down(s2, off);
  }
  if (lane == 0) {
    int wi = (s2 < s1 || (s2 == s1 && bi2 < bi1)) ? bi2 : bi1;
    win[b] = wi;
    out_idx[b] = (float)wi;   // f32 output; ref bf16-rounds 4095->4096, |diff|<=1 << 81.92
  }
}

// --------- out0[b,:] = f32 G[:, win[b]]  (G is [OUT][HID] row-major) ---------
__global__ void __launch_bounds__(256)
gather_kernel(const float* __restrict__ G, const int* __restrict__ win,
              float* __restrict__ out0) {
  int b = blockIdx.x;
  int w = win[b];
  w = (w < 0) ? 0 : (w > HID - 1 ? HID - 1 : w);  // no OOB reads from out0 path
#pragma unroll
  for (int i = 0; i < OUT / 256; ++i) {
    int o = threadIdx.x + i * 256;
    out0[(size_t)b * OUT + o] = G[(size_t)o * HID + w];
  }
}

extern "C" void kernel_launch(void* const* d_in, const int* in_sizes, int n_in,
                              void* d_out, int out_size, void* d_ws, size_t ws_size,
                              hipStream_t stream) {
  const float* X = (const float*)d_in[0];
  const float* W = (const float*)d_in[1];  // kohonen [HID][KDIM]
  const float* G = (const float*)d_in[2];  // grossberg [OUT][HID]
  float* out0 = (float*)d_out;                      // [BATCH][OUT] f32
  float* out_idx = out0 + (size_t)BATCH * OUT;      // [BATCH] f32 indices

  char* ws = (char*)d_ws;
  float* w2 = (float*)ws;                                   // 16 KB
  float4* partials = (float4*)(ws + 16 * 1024);             // 8192*8*16 = 1 MB
  int* win = (int*)(ws + 16 * 1024 + (size_t)BATCH * NCHUNK * 16);  // 32 KB

  w2_kernel<<<HID, 64, 0, stream>>>(W, w2);
  dist_argmin_kernel<<<512, 256, 0, stream>>>(X, W, w2, partials);
  recheck_kernel<<<BATCH / 4, 256, 0, stream>>>(X, W, partials, win, out_idx);
  gather_kernel<<<BATCH, 256, 0, stream>>>(G, win, out0);
}